// Round 12
// baseline (182.490 us; speedup 1.0000x reference)
//
#include <hip/hip_runtime.h>
#include <hip/hip_bf16.h>

// x: [4, 4096, 4096] f32, W1: [48, 4096] f32, W2: [48, 48] f32
// out: [4, 4, 4096, 12] f32  (C, B, T, L/C)
#define DDIM 4096
#define LTOT 48

typedef __attribute__((ext_vector_type(4))) float f32x4;
typedef __attribute__((ext_vector_type(8))) short bf16x8;

__device__ __forceinline__ void gload_lds16(const void* g, void* l) {
    __builtin_amdgcn_global_load_lds(
        (const __attribute__((address_space(1))) void*)g,
        (__attribute__((address_space(3))) void*)l, 16, 0, 0);
}

__device__ __forceinline__ unsigned cvt_pk(float x, float y) {
    union { __hip_bfloat162 h; unsigned u; } c;
    c.h = __float22bfloat162_rn(make_float2(x, y));
    return c.u;
}

// ---- kernel 0: W1 fp32 -> bf16 (RNE) into workspace ----
__global__ void w1cvt_kernel(const float* __restrict__ w1, ushort* __restrict__ w1b) {
    int i = blockIdx.x * 256 + threadIdx.x;
    union { float f; unsigned u; } v; v.f = w1[i];
    unsigned r = v.u + 0x7fffu + ((v.u >> 16) & 1u);
    w1b[i] = (ushort)(r >> 16);
}

// ---- PURE-READ CEILING PROBE (sacrificial, rule #10): canonical grid-stride
// float4 streaming read of x, 3 passes = 804 MB logical (>256MB L3 ->
// cyclic eviction -> HBM). Lands in rocprof top-5 (~160us > 151us fills)
// so its dur_us / FETCH_SIZE / hbm_gbps row is directly visible.
// Writes wave-reduced sums into the w1b region (dead after fused_kernel;
// w1cvt re-creates it every replay -> deterministic).
__global__ __launch_bounds__(256) void readprobe_kernel(
        const float* __restrict__ x, float* __restrict__ sink) {
    const size_t N4 = (size_t)4 * 4096 * 4096 / 4;   // 16,777,216 float4
    const size_t nth = (size_t)gridDim.x * 256;
    size_t tid = (size_t)blockIdx.x * 256 + threadIdx.x;
    const f32x4* xv = (const f32x4*)x;
    f32x4 acc = {0.f, 0.f, 0.f, 0.f};
    #pragma unroll 1
    for (int p = 0; p < 3; ++p) {
        #pragma unroll 4
        for (size_t i = tid; i < N4; i += nth)
            acc += xv[i];
    }
    float s = acc.x + acc.y + acc.z + acc.w;
    s += __shfl_xor(s, 1);  s += __shfl_xor(s, 2);  s += __shfl_xor(s, 4);
    s += __shfl_xor(s, 8);  s += __shfl_xor(s, 16); s += __shfl_xor(s, 32);
    if ((threadIdx.x & 63) == 0)
        sink[(blockIdx.x * 4) + (threadIdx.x >> 6)] = s;
}

// ---- fused: 32-row blocks (2 MFMA row-tiles/wave), 4-wave K-split,
//      DMA-staged double buffer (round-10 verbatim, session best) ----
__global__ __launch_bounds__(256, 2) void fused_kernel(
        const float* __restrict__ x,
        const ushort* __restrict__ w1b,
        const float* __restrict__ w2,
        float* __restrict__ out) {
    // staging: 4 waves x 2 buffers x 8192B (32 rows x 64 f32, XOR-swizzled)
    __shared__ __align__(1024) char smem[65536];
    __shared__ float ssw[4][32];
    __shared__ float scl[32];

    const int tid  = threadIdx.x;
    const int wave = tid >> 6;
    const int lane = tid & 63;
    const int rl   = lane & 15;   // A-row (within tile) / B-row / C-col
    const int kg   = lane >> 4;   // k-group 0..3
    const int row0 = blockIdx.x * 32;
    const int kw   = wave * 1024; // per-wave K range
    const int rot  = blockIdx.x & 15;

    char* wbase = smem + wave * 16384;

    int dso[2][2][2];
    #pragma unroll
    for (int T = 0; T < 2; ++T)
        #pragma unroll
        for (int h = 0; h < 2; ++h)
            #pragma unroll
            for (int p = 0; p < 2; ++p)
                dso[T][h][p] = (T * 16 + rl) * 256 + (((h * 8 + kg * 2 + p) ^ rl) << 4);

    auto stage = [&](int t) {
        const int kb = kw + ((t + rot) & 15) * 64;
        char* lb = wbase + (t & 1) * 8192;
        #pragma unroll
        for (int i = 0; i < 8; ++i) {
            int r    = i * 4 + kg;           // row this lane's 16B lands in
            int blkg = rl ^ (r & 15);        // source block (inverse swizzle)
            const float* src = x + (size_t)(row0 + r) * DDIM + kb + blkg * 4;
            gload_lds16(src, lb + i * 1024);
        }
    };

    auto loadB = [&](int s, bf16x8 (&bl)[6]) {
        const ushort* bp = w1b + (size_t)rl * DDIM + kw + ((s + rot) & 15) * 64 + kg * 8;
        #pragma unroll
        for (int n = 0; n < 3; ++n)
            #pragma unroll
            for (int h = 0; h < 2; ++h)
                bl[n * 2 + h] = *(const bf16x8*)(bp + n * 16 * DDIM + h * 32);
    };

    float ss0 = 0.f, ss1 = 0.f;
    f32x4 acc0[3] = {{0.f,0.f,0.f,0.f},{0.f,0.f,0.f,0.f},{0.f,0.f,0.f,0.f}};
    f32x4 acc1[3] = {{0.f,0.f,0.f,0.f},{0.f,0.f,0.f,0.f},{0.f,0.f,0.f,0.f}};
    bf16x8 bA[6], bB[6];

    stage(0); loadB(0, bA); stage(1);

    auto body = [&](int s, bf16x8 (&bu)[6], bf16x8 (&bl)[6]) {
        if (s == 0)       asm volatile("s_waitcnt vmcnt(14)" ::: "memory");
        else if (s == 15) asm volatile("s_waitcnt vmcnt(6)"  ::: "memory");
        else              asm volatile("s_waitcnt vmcnt(8)"  ::: "memory");
        char* lb = wbase + (s & 1) * 8192;
        f32x4 a[2][2][2];
        #pragma unroll
        for (int T = 0; T < 2; ++T)
            #pragma unroll
            for (int h = 0; h < 2; ++h)
                #pragma unroll
                for (int p = 0; p < 2; ++p)
                    a[T][h][p] = *(const f32x4*)(lb + dso[T][h][p]);
        if (s < 15) loadB(s + 1, bl);
        #pragma unroll
        for (int h = 0; h < 2; ++h) {
            f32x4 a0 = a[0][h][0], a1 = a[0][h][1];
            f32x4 c0 = a[1][h][0], c1 = a[1][h][1];
            ss0 = fmaf(a0.x, a0.x, ss0); ss0 = fmaf(a0.y, a0.y, ss0);
            ss0 = fmaf(a0.z, a0.z, ss0); ss0 = fmaf(a0.w, a0.w, ss0);
            ss0 = fmaf(a1.x, a1.x, ss0); ss0 = fmaf(a1.y, a1.y, ss0);
            ss0 = fmaf(a1.z, a1.z, ss0); ss0 = fmaf(a1.w, a1.w, ss0);
            ss1 = fmaf(c0.x, c0.x, ss1); ss1 = fmaf(c0.y, c0.y, ss1);
            ss1 = fmaf(c0.z, c0.z, ss1); ss1 = fmaf(c0.w, c0.w, ss1);
            ss1 = fmaf(c1.x, c1.x, ss1); ss1 = fmaf(c1.y, c1.y, ss1);
            ss1 = fmaf(c1.z, c1.z, ss1); ss1 = fmaf(c1.w, c1.w, ss1);
            union { bf16x8 v; unsigned u[4]; } af, ag;
            af.u[0] = cvt_pk(a0.x, a0.y); af.u[1] = cvt_pk(a0.z, a0.w);
            af.u[2] = cvt_pk(a1.x, a1.y); af.u[3] = cvt_pk(a1.z, a1.w);
            ag.u[0] = cvt_pk(c0.x, c0.y); ag.u[1] = cvt_pk(c0.z, c0.w);
            ag.u[2] = cvt_pk(c1.x, c1.y); ag.u[3] = cvt_pk(c1.z, c1.w);
            #pragma unroll
            for (int n = 0; n < 3; ++n) {
                acc0[n] = __builtin_amdgcn_mfma_f32_16x16x32_bf16(
                              af.v, bu[n * 2 + h], acc0[n], 0, 0, 0);
                acc1[n] = __builtin_amdgcn_mfma_f32_16x16x32_bf16(
                              ag.v, bu[n * 2 + h], acc1[n], 0, 0, 0);
            }
        }
        asm volatile("s_waitcnt lgkmcnt(0)" ::: "memory");
        if (s < 14) stage(s + 2);
    };

    for (int sp = 0; sp < 8; ++sp) {
        body(2 * sp,     bA, bB);
        body(2 * sp + 1, bB, bA);
    }

    ss0 += __shfl_xor(ss0, 16); ss0 += __shfl_xor(ss0, 32);
    ss1 += __shfl_xor(ss1, 16); ss1 += __shfl_xor(ss1, 32);
    if (lane < 16) { ssw[wave][lane] = ss0; ssw[wave][16 + lane] = ss1; }

    asm volatile("s_waitcnt vmcnt(0) lgkmcnt(0)" ::: "memory");
    __syncthreads();

    float* dots = (float*)smem;             // [4][32][48] = 24576 B
    float* gbuf = (float*)(smem + 24576);   // [32][48]    =  6144 B
    float* w2s  = (float*)(smem + 30720);   // [48][48]    =  9216 B

    #pragma unroll
    for (int n = 0; n < 3; ++n)
        #pragma unroll
        for (int i = 0; i < 4; ++i) {
            dots[(wave * 32 + kg * 4 + i) * 48 + n * 16 + rl]      = acc0[n][i];
            dots[(wave * 32 + 16 + kg * 4 + i) * 48 + n * 16 + rl] = acc1[n][i];
        }
    for (int i = tid; i < LTOT * LTOT; i += 256) w2s[i] = w2[i];
    if (tid < 32) {
        float st = ssw[0][tid] + ssw[1][tid] + ssw[2][tid] + ssw[3][tid];
        scl[tid] = rsqrtf(st * (1.0f / (float)DDIM) + 1e-5f);
    }
    __syncthreads();

    #pragma unroll
    for (int i = 0; i < 6; ++i) {
        int v = tid + i * 256;                 // 0..1535 = 32*48
        int row = v / 48, col = v - row * 48;
        float d = dots[(0 * 32 + row) * 48 + col] + dots[(1 * 32 + row) * 48 + col]
                + dots[(2 * 32 + row) * 48 + col] + dots[(3 * 32 + row) * 48 + col];
        float h = d * scl[row];
        gbuf[row * 48 + col] = h * 0.5f * (1.0f + erff(h * 0.70710678118654752f));
    }
    __syncthreads();

    #pragma unroll
    for (int i = 0; i < 6; ++i) {
        int v = tid + i * 256;
        int row = v / 48, l = v - row * 48;
        float sacc = 0.f;
        #pragma unroll
        for (int k = 0; k < LTOT; ++k)
            sacc = fmaf(gbuf[row * 48 + k], w2s[l * LTOT + k], sacc);
        int rg = row0 + row;
        int b  = rg >> 12;
        int t  = rg & 4095;
        int c  = l / 12, j = l - c * 12;
        out[(((size_t)(c * 4 + b) * 4096 + t) * 12) + j] = sacc;
    }
}

extern "C" void kernel_launch(void* const* d_in, const int* in_sizes, int n_in,
                              void* d_out, int out_size, void* d_ws, size_t ws_size,
                              hipStream_t stream) {
    const float* x  = (const float*)d_in[0];
    const float* W1 = (const float*)d_in[1];
    const float* W2 = (const float*)d_in[2];
    float* out = (float*)d_out;
    ushort* w1b = (ushort*)d_ws;

    w1cvt_kernel<<<(LTOT * DDIM) / 256, 256, 0, stream>>>(W1, w1b);
    fused_kernel<<<16384 / 32, 256, 0, stream>>>(x, w1b, W2, out);
    // sacrificial pure-read ceiling probe (reuses w1b region as sink;
    // w1cvt rewrites it on every replay -> deterministic)
    readprobe_kernel<<<2048, 256, 0, stream>>>(x, (float*)d_ws);
}